// Round 9
// baseline (77.829 us; speedup 1.0000x reference)
//
#include <hip/hip_runtime.h>
#include <math.h>

#define NQ 14
#define NSTATE (1 << 14)
#define DEPTH  6
#define NT     1024             // 16 waves/block

// dword-index swizzle: banks b2^=d6^d10, b3^=d7^d12, b4^=d8^d13 (GF(2)-linear)
__device__ __host__ constexpr int swz3(int n) {
    return n ^ ((n >> 4) & 28) ^ ((n >> 8) & 4) ^ ((n >> 9) & 24);
}

// fused CNOT ladders (even after odd): m = sigma_e(sigma_o(n))
__device__ __host__ constexpr int sigma(int n) {
    int m = n ^ ((n & 0x1554) >> 1);
    return m ^ ((m & 0x2AAA) >> 1);
}

// RY on p-index bit JB over a 16-amp real register block
template <int JB>
__device__ __forceinline__ void ry16(float (&p)[16], float c, float s) {
#pragma unroll
    for (int i = 0; i < 16; ++i) {
        if (!((i >> JB) & 1)) {
            const int i1 = i | (1 << JB);
            float a0 = p[i], a1 = p[i1];
            p[i]  = c * a0 - s * a1;
            p[i1] = s * a0 + c * a1;
        }
    }
}

// RY across lane bit 0/1 via DPP quad_perm (VALU pipe).
// CTRL: 0xB1 = xor lane^1, 0x4E = xor lane^2.  sg = (lane bit set)? +s : -s
template <int CTRL>
__device__ __forceinline__ void ry_dpp(float (&p)[16], float c, float sg) {
#pragma unroll
    for (int i = 0; i < 16; ++i) {
        float partner = __int_as_float(__builtin_amdgcn_update_dpp(
            0, __float_as_int(p[i]), CTRL, 0xF, 0xF, true));
        p[i] = c * p[i] + sg * partner;
    }
}

// RY across lane bit 4 (permlane16_swap) / 5 (permlane32_swap), VALU pipe.
// Labeling-invariant: under any bit-B exchange, {o0,o1} = {own, partner}
// per lane, so partner = o0 + o1 - own and
//   p_new = c*own + sg*partner = (c - sg)*own + sg*(o0 + o1),
// with sg = (lane bit set) ? +s : -s.  Pass cms = c - sg.
template <bool SIXTEEN>
__device__ __forceinline__ void ry_pl(float (&p)[16], float cms, float sg) {
#pragma unroll
    for (int i = 0; i < 16; ++i) {
        float o0 = p[i], o1 = p[i];
        if constexpr (SIXTEEN)
            asm("v_permlane16_swap_b32 %0, %1" : "+v"(o0), "+v"(o1));
        else
            asm("v_permlane32_swap_b32 %0, %1" : "+v"(o0), "+v"(o1));
        p[i] = cms * p[i] + sg * (o0 + o1);
    }
}

__global__ __launch_bounds__(NT, 4)
void vqc_kernel(const float* __restrict__ X,    // (512,14)
                const float* __restrict__ TH,   // (6,14)
                const float* __restrict__ A,    // (14,28)
                const float* __restrict__ Bc,   // (14,28)  unused: state stays real
                const float* __restrict__ D,    // (14,8)
                float* __restrict__ out)        // (512,2)
{
    __shared__ __align__(16) float st[NSTATE];  // 64 KiB real state
    __shared__ float2 tb[DEPTH * NQ];           // (cos,sin) per theta
    __shared__ float2 xf[NQ];                   // (c-s, c+s) per amplitude bit j
    __shared__ float  red[2 * (NT / 64)];

    const int t = threadIdx.x;
    const int b = blockIdx.x;

    // ---- trig tables (uniform work once per block) ----
    if (t < DEPTH * NQ) {
        float s, c;
        __sincosf(0.5f * TH[t], &s, &c);
        tb[t] = make_float2(c, s);
    } else if (t < DEPTH * NQ + NQ) {
        const int j = t - DEPTH * NQ;           // amplitude-bit j <-> wire 13-j
        float s, c;
        __sincosf(0.5f * X[b * NQ + (13 - j)], &s, &c);
        xf[j] = make_float2(c - s, c + s);
    }
    __syncthreads();

    // ---- layer 0 P1: product state at sigma(n) + rotations {13..10,9,8,5,4} ----
    {
        const int mt = sigma(t << 4);
        float sh = 1.0f / 128.0f;
#pragma unroll
        for (int j = 4; j < 14; ++j) {
            float2 f = xf[j];
            sh *= ((mt >> j) & 1) ? f.y : f.x;
        }
        float fa[4], fb[4];
#pragma unroll
        for (int j = 0; j < 4; ++j) {
            float2 f = xf[j];
            const int mj = (mt >> j) & 1;
            fa[j] = mj ? f.y : f.x;
            fb[j] = mj ? f.x : f.y;
        }
        float p[16];
#pragma unroll
        for (int i = 0; i < 16; ++i) {
            const int sl = sigma(i);
            float v = sh;
            v *= (sl & 1)        ? fb[0] : fa[0];
            v *= ((sl >> 1) & 1) ? fb[1] : fa[1];
            v *= ((sl >> 2) & 1) ? fb[2] : fa[2];
            v *= ((sl >> 3) & 1) ? fb[3] : fa[3];
            p[i] = v;
        }
        float2 q0 = tb[13], q1 = tb[12], q2 = tb[11], q3 = tb[10];
        ry16<0>(p, q0.x, q0.y);
        ry16<1>(p, q1.x, q1.y);
        ry16<2>(p, q2.x, q2.y);
        ry16<3>(p, q3.x, q3.y);
        // lane rotations: wire9 (amp4=lane0), wire8 (amp5=lane1),
        //                 wire5 (amp8=lane4), wire4 (amp9=lane5)
        {
            float2 w9 = tb[9], w8 = tb[8], w5 = tb[5], w4 = tb[4];
            const float sg9 = (t & 1)        ? w9.y : -w9.y;
            const float sg8 = ((t >> 1) & 1) ? w8.y : -w8.y;
            const float sg5 = ((t >> 4) & 1) ? w5.y : -w5.y;
            const float sg4 = ((t >> 5) & 1) ? w4.y : -w4.y;
            ry_dpp<0xB1>(p, w9.x, sg9);
            ry_dpp<0x4E>(p, w8.x, sg8);
            ry_pl<true >(p, w5.x - sg5, sg5);
            ry_pl<false>(p, w4.x - sg4, sg4);
        }
        const int wb = swz3(t << 4);
#pragma unroll
        for (int g = 0; g < 4; ++g)
            *(float4*)&st[wb ^ (g << 2)] =
                make_float4(p[4 * g], p[4 * g + 1], p[4 * g + 2], p[4 * g + 3]);
    }
    __syncthreads();

    // ---- layers: P1 (CNOT + 8 wires), P2 (6 wires, in-place) ----
    for (int k = 0; k < DEPTH; ++k) {
        const float2* tbk = tb + k * NQ;

        if (k > 0) {
            // P1: gather through sigma (b128), rotate, write std (b128)
            const int bstart = sigma(t << 4) & ~15;
            const int rb = swz3(bstart);
            float tmp[16];
#pragma unroll
            for (int g = 0; g < 4; ++g)
                *(float4*)&tmp[g * 4] = *(const float4*)&st[rb ^ (g << 2)];
            const int t0 = t & 1;
            float p[16];
#pragma unroll
            for (int i = 0; i < 16; ++i) {
                const int i0 = i & 1, i1 = (i >> 1) & 1, i2 = (i >> 2) & 1, i3 = (i >> 3) & 1;
                const int s = (i0 ^ i1 ^ i2) | ((i1 ^ i2) << 1) | ((i2 ^ i3) << 2) | (i3 << 3);
                p[i] = t0 ? tmp[s ^ 12] : tmp[s];
            }
            __syncthreads();                     // all gather-reads before any write
            float2 q0 = tbk[13], q1 = tbk[12], q2 = tbk[11], q3 = tbk[10];
            ry16<0>(p, q0.x, q0.y);
            ry16<1>(p, q1.x, q1.y);
            ry16<2>(p, q2.x, q2.y);
            ry16<3>(p, q3.x, q3.y);
            {
                float2 w9 = tbk[9], w8 = tbk[8], w5 = tbk[5], w4 = tbk[4];
                const float sg9 = (t & 1)        ? w9.y : -w9.y;
                const float sg8 = ((t >> 1) & 1) ? w8.y : -w8.y;
                const float sg5 = ((t >> 4) & 1) ? w5.y : -w5.y;
                const float sg4 = ((t >> 5) & 1) ? w4.y : -w4.y;
                ry_dpp<0xB1>(p, w9.x, sg9);
                ry_dpp<0x4E>(p, w8.x, sg8);
                ry_pl<true >(p, w5.x - sg5, sg5);
                ry_pl<false>(p, w4.x - sg4, sg4);
            }
            const int wb = swz3(t << 4);
#pragma unroll
            for (int g = 0; g < 4; ++g)
                *(float4*)&st[wb ^ (g << 2)] =
                    make_float4(p[4 * g], p[4 * g + 1], p[4 * g + 2], p[4 * g + 3]);
            __syncthreads();
        }

        // P2: in-place RMW. regs = amp bits 4-7; rotate wires 7,6 (amp 6,7 reg),
        // wire3 (amp10=lane4), wire2 (amp11=lane5), wire1 (amp12=lane0), wire0 (amp13=lane1)
        {
            const int F2 = ((t >> 2) & 3) | (((t >> 6) & 3) << 2) | (((t >> 8) & 3) << 8)
                         | ((t & 0x30) << 6) | ((t & 3) << 12);
            const int base = swz3(F2);
            float p[16];
#pragma unroll
            for (int i = 0; i < 16; ++i) p[i] = st[base ^ swz3(i << 4)];
            float2 q2 = tbk[7], q3 = tbk[6];
            ry16<2>(p, q2.x, q2.y);             // amp bit 6 <-> wire 7
            ry16<3>(p, q3.x, q3.y);             // amp bit 7 <-> wire 6
            {
                float2 w3 = tbk[3], w2 = tbk[2], w1 = tbk[1], w0 = tbk[0];
                const float sg3 = ((t >> 4) & 1) ? w3.y : -w3.y;
                const float sg2 = ((t >> 5) & 1) ? w2.y : -w2.y;
                const float sg1 = (t & 1)        ? w1.y : -w1.y;
                const float sg0 = ((t >> 1) & 1) ? w0.y : -w0.y;
                ry_pl<true >(p, w3.x - sg3, sg3);
                ry_pl<false>(p, w2.x - sg2, sg2);
                ry_dpp<0xB1>(p, w1.x, sg1);
                ry_dpp<0x4E>(p, w0.x, sg0);
            }
#pragma unroll
            for (int i = 0; i < 16; ++i) st[base ^ swz3(i << 4)] = p[i];
            __syncthreads();
        }
    }

    // ---- expectations (real state: B drops out) ----
    float e[2];
#pragma unroll
    for (int q = 0; q < 2; ++q) {
        const int shift = 11 - q;
        float dg[8];
#pragma unroll
        for (int i = 0; i < 7; ++i) dg[i] = 2.0f * D[q * 8 + i + 1];
        dg[7] = 0.0f;
        float acc = 0.0f;
        const int lowmask = (1 << shift) - 1;
        for (int r = t; r < NSTATE / 8; r += NT) {   // 2 iterations
            const int base = ((r >> shift) << (shift + 3)) | (r & lowmask);
            float ps[8];
#pragma unroll
            for (int i = 0; i < 8; ++i) ps[i] = st[swz3(base + (i << shift))];
#pragma unroll
            for (int i = 0; i < 8; ++i) acc += dg[i] * ps[i] * ps[i];
            int kk = 0;
#pragma unroll
            for (int i = 1; i < 8; ++i)
#pragma unroll
                for (int j = 0; j < i; ++j, ++kk)
                    acc += 2.0f * A[q * 28 + kk] * ps[i] * ps[j];
        }
        e[q] = acc;
    }

    // ---- block reduction ----
    float v0 = e[0], v1 = e[1];
#pragma unroll
    for (int o = 32; o > 0; o >>= 1) {
        v0 += __shfl_down(v0, o);
        v1 += __shfl_down(v1, o);
    }
    if ((t & 63) == 0) {
        red[(t >> 6) * 2]     = v0;
        red[(t >> 6) * 2 + 1] = v1;
    }
    __syncthreads();
    if (t == 0) {
        float s0 = 0.0f, s1 = 0.0f;
#pragma unroll
        for (int i = 0; i < NT / 64; ++i) { s0 += red[i * 2]; s1 += red[i * 2 + 1]; }
        out[b * 2 + 0] = s0;
        out[b * 2 + 1] = s1;
    }
}

extern "C" void kernel_launch(void* const* d_in, const int* in_sizes, int n_in,
                              void* d_out, int out_size, void* d_ws, size_t ws_size,
                              hipStream_t stream) {
    const float* X  = (const float*)d_in[0];
    const float* TH = (const float*)d_in[1];
    const float* A  = (const float*)d_in[2];
    const float* Bc = (const float*)d_in[3];
    const float* D  = (const float*)d_in[4];
    float* out = (float*)d_out;
    vqc_kernel<<<512, NT, 0, stream>>>(X, TH, A, Bc, D, out);
}

// Round 10
// 48.002 us; speedup vs baseline: 1.6214x; 1.6214x over previous
//
#include <hip/hip_runtime.h>
#include <math.h>

#define NQ 14
#define NSTATE (1 << 14)
#define DEPTH  6
#define NT     1024             // 16 waves/block

// dword-index swizzle: XOR bits 6,7,8 into 2,3,4 (GF(2)-linear)
__device__ __forceinline__ int swz(int n) { return n ^ ((n >> 4) & 28); }

// fused CNOT ladders (even after odd): m = sigma_e(sigma_o(n))
__device__ __forceinline__ int sigma(int n) {
    int m = n ^ ((n & 0x1554) >> 1);
    return m ^ ((m & 0x2AAA) >> 1);
}

// RY on p-index bit JB over a 16-amp real register block
template <int JB>
__device__ __forceinline__ void ry16(float (&p)[16], float c, float s) {
#pragma unroll
    for (int i = 0; i < 16; ++i) {
        if (!((i >> JB) & 1)) {
            const int i1 = i | (1 << JB);
            float a0 = p[i], a1 = p[i1];
            p[i]  = c * a0 - s * a1;
            p[i1] = s * a0 + c * a1;
        }
    }
}

// RY across lane bit 0/1 via DPP quad_perm (VALU pipe, verified r9).
// CTRL: 0xB1 = xor lane^1, 0x4E = xor lane^2.  sg = (lane bit set)? +s : -s
template <int CTRL>
__device__ __forceinline__ void ry_dpp(float (&p)[16], float c, float sg) {
#pragma unroll
    for (int i = 0; i < 16; ++i) {
        float partner = __int_as_float(__builtin_amdgcn_update_dpp(
            0, __float_as_int(p[i]), CTRL, 0xF, 0xF, true));
        p[i] = c * p[i] + sg * partner;
    }
}

__global__ __launch_bounds__(NT, 4)
void vqc_kernel(const float* __restrict__ X,    // (512,14)
                const float* __restrict__ TH,   // (6,14)
                const float* __restrict__ A,    // (14,28)
                const float* __restrict__ Bc,   // (14,28)  unused: state stays real
                const float* __restrict__ D,    // (14,8)
                float* __restrict__ out)        // (512,2)
{
    __shared__ __align__(16) float st[NSTATE];  // 64 KiB real state
    __shared__ float2 tb[DEPTH * NQ];           // (cos,sin) per theta
    __shared__ float2 xf[NQ];                   // (c-s, c+s) per amplitude bit j
    __shared__ float  red[2 * (NT / 64)];

    const int t = threadIdx.x;
    const int b = blockIdx.x;

    // ---- trig tables (uniform work once per block) ----
    if (t < DEPTH * NQ) {
        float s, c;
        __sincosf(0.5f * TH[t], &s, &c);
        tb[t] = make_float2(c, s);
    } else if (t < DEPTH * NQ + NQ) {
        const int j = t - DEPTH * NQ;           // amplitude-bit j <-> wire 13-j
        float s, c;
        __sincosf(0.5f * X[b * NQ + (13 - j)], &s, &c);
        xf[j] = make_float2(c - s, c + s);
    }
    __syncthreads();

    // ---- layer 0 P1: product state at sigma(n), rotate wires 13..10 (amp 0-3) ----
    {
        const int mt = sigma(t << 4);
        float sh = 1.0f / 128.0f;
#pragma unroll
        for (int j = 4; j < 14; ++j) {
            float2 f = xf[j];
            sh *= ((mt >> j) & 1) ? f.y : f.x;
        }
        float fa[4], fb[4];
#pragma unroll
        for (int j = 0; j < 4; ++j) {
            float2 f = xf[j];
            const int mj = (mt >> j) & 1;
            fa[j] = mj ? f.y : f.x;
            fb[j] = mj ? f.x : f.y;
        }
        float p[16];
#pragma unroll
        for (int i = 0; i < 16; ++i) {
            const int sl = sigma(i);
            float v = sh;
            v *= (sl & 1)        ? fb[0] : fa[0];
            v *= ((sl >> 1) & 1) ? fb[1] : fa[1];
            v *= ((sl >> 2) & 1) ? fb[2] : fa[2];
            v *= ((sl >> 3) & 1) ? fb[3] : fa[3];
            p[i] = v;
        }
        float2 q0 = tb[13], q1 = tb[12], q2 = tb[11], q3 = tb[10];
        ry16<0>(p, q0.x, q0.y);
        ry16<1>(p, q1.x, q1.y);
        ry16<2>(p, q2.x, q2.y);
        ry16<3>(p, q3.x, q3.y);
        const int wb = swz(t << 4);
#pragma unroll
        for (int g = 0; g < 4; ++g)
            *(float4*)&st[wb ^ (g << 2)] =
                make_float4(p[4 * g], p[4 * g + 1], p[4 * g + 2], p[4 * g + 3]);
    }
    __syncthreads();

    // ---- layers: P1 (CNOT + wires 13-10), P2 (9-6 reg + 5,4 DPP), P3 (3-0) ----
    for (int k = 0; k < DEPTH; ++k) {
        const float2* tbk = tb + k * NQ;

        if (k > 0) {
            // P1: gather through sigma (b128), rotate amp 0-3, write std (b128)
            const int rb = swz(sigma(t << 4) & ~15);
            float tmp[16];
#pragma unroll
            for (int g = 0; g < 4; ++g)
                *(float4*)&tmp[g * 4] = *(const float4*)&st[rb ^ (g << 2)];
            const int t0 = t & 1;
            float p[16];
#pragma unroll
            for (int i = 0; i < 16; ++i) {
                const int i0 = i & 1, i1 = (i >> 1) & 1, i2 = (i >> 2) & 1, i3 = (i >> 3) & 1;
                const int s = (i0 ^ i1 ^ i2) | ((i1 ^ i2) << 1) | ((i2 ^ i3) << 2) | (i3 << 3);
                p[i] = t0 ? tmp[s ^ 12] : tmp[s];
            }
            __syncthreads();                     // all gather-reads before any write
            float2 q0 = tbk[13], q1 = tbk[12], q2 = tbk[11], q3 = tbk[10];
            ry16<0>(p, q0.x, q0.y);
            ry16<1>(p, q1.x, q1.y);
            ry16<2>(p, q2.x, q2.y);
            ry16<3>(p, q3.x, q3.y);
            const int wb = swz(t << 4);
#pragma unroll
            for (int g = 0; g < 4; ++g)
                *(float4*)&st[wb ^ (g << 2)] =
                    make_float4(p[4 * g], p[4 * g + 1], p[4 * g + 2], p[4 * g + 3]);
            __syncthreads();
        }

        // P2: in-place RMW. regs = amp 4-7 (wires 9-6); DPP lanes t0,t1 = amp 8,9
        // (wires 5,4). Pairs over amp bit 5 -> additive +32 dwords (ds_read2).
        {
            const int raw = ((t >> 2) & 15) | ((t & 1) << 8) | ((t & 2) << 8)
                          | (((t >> 6) & 15) << 10);
            const int base2 = swz(raw);
            float p[16];
#pragma unroll
            for (int ip = 0; ip < 16; ++ip) {
                if ((ip & 2) == 0) {
                    const int v = base2 ^ (ip << 4) ^ (ip & 12);   // swz(ip<<4) folded
                    p[ip]     = st[v];
                    p[ip | 2] = st[v + 32];
                }
            }
            float2 q0 = tbk[9], q1 = tbk[8], q2 = tbk[7], q3 = tbk[6];
            ry16<0>(p, q0.x, q0.y);             // amp4 <-> wire 9
            ry16<1>(p, q1.x, q1.y);             // amp5 <-> wire 8
            ry16<2>(p, q2.x, q2.y);             // amp6 <-> wire 7
            ry16<3>(p, q3.x, q3.y);             // amp7 <-> wire 6
            float2 w5 = tbk[5], w4 = tbk[4];
            const float sg5 = (t & 1) ? w5.y : -w5.y;   // amp8 = lane bit 0
            const float sg4 = (t & 2) ? w4.y : -w4.y;   // amp9 = lane bit 1
            ry_dpp<0xB1>(p, w5.x, sg5);
            ry_dpp<0x4E>(p, w4.x, sg4);
#pragma unroll
            for (int ip = 0; ip < 16; ++ip) {
                if ((ip & 2) == 0) {
                    const int v = base2 ^ (ip << 4) ^ (ip & 12);
                    st[v]      = p[ip];
                    st[v + 32] = p[ip | 2];
                }
            }
            __syncthreads();
        }

        // P3: in-place RMW. regs = amp 10-13 (wires 3-0). Addresses purely
        // additive: base + i*1024 dwords (swz untouched) -> read2st64 / imm offsets.
        {
            const int base3 = swz(t);
            float p[16];
#pragma unroll
            for (int i = 0; i < 16; ++i) p[i] = st[base3 + (i << 10)];
            float2 q0 = tbk[3], q1 = tbk[2], q2 = tbk[1], q3 = tbk[0];
            ry16<0>(p, q0.x, q0.y);             // amp10 <-> wire 3
            ry16<1>(p, q1.x, q1.y);             // amp11 <-> wire 2
            ry16<2>(p, q2.x, q2.y);             // amp12 <-> wire 1
            ry16<3>(p, q3.x, q3.y);             // amp13 <-> wire 0
#pragma unroll
            for (int i = 0; i < 16; ++i) st[base3 + (i << 10)] = p[i];
            __syncthreads();
        }
    }

    // ---- expectations (real state: B drops out) ----
    float e[2];
#pragma unroll
    for (int q = 0; q < 2; ++q) {
        const int shift = 11 - q;
        float dg[8];
#pragma unroll
        for (int i = 0; i < 7; ++i) dg[i] = 2.0f * D[q * 8 + i + 1];
        dg[7] = 0.0f;
        float acc = 0.0f;
        const int lowmask = (1 << shift) - 1;
        for (int r = t; r < NSTATE / 8; r += NT) {   // 2 iterations
            const int base = ((r >> shift) << (shift + 3)) | (r & lowmask);
            float ps[8];
#pragma unroll
            for (int i = 0; i < 8; ++i) ps[i] = st[swz(base + (i << shift))];
#pragma unroll
            for (int i = 0; i < 8; ++i) acc += dg[i] * ps[i] * ps[i];
            int kk = 0;
#pragma unroll
            for (int i = 1; i < 8; ++i)
#pragma unroll
                for (int j = 0; j < i; ++j, ++kk)
                    acc += 2.0f * A[q * 28 + kk] * ps[i] * ps[j];
        }
        e[q] = acc;
    }

    // ---- block reduction ----
    float v0 = e[0], v1 = e[1];
#pragma unroll
    for (int o = 32; o > 0; o >>= 1) {
        v0 += __shfl_down(v0, o);
        v1 += __shfl_down(v1, o);
    }
    if ((t & 63) == 0) {
        red[(t >> 6) * 2]     = v0;
        red[(t >> 6) * 2 + 1] = v1;
    }
    __syncthreads();
    if (t == 0) {
        float s0 = 0.0f, s1 = 0.0f;
#pragma unroll
        for (int i = 0; i < NT / 64; ++i) { s0 += red[i * 2]; s1 += red[i * 2 + 1]; }
        out[b * 2 + 0] = s0;
        out[b * 2 + 1] = s1;
    }
}

extern "C" void kernel_launch(void* const* d_in, const int* in_sizes, int n_in,
                              void* d_out, int out_size, void* d_ws, size_t ws_size,
                              hipStream_t stream) {
    const float* X  = (const float*)d_in[0];
    const float* TH = (const float*)d_in[1];
    const float* A  = (const float*)d_in[2];
    const float* Bc = (const float*)d_in[3];
    const float* D  = (const float*)d_in[4];
    float* out = (float*)d_out;
    vqc_kernel<<<512, NT, 0, stream>>>(X, TH, A, Bc, D, out);
}